// Round 4
// baseline (321.518 us; speedup 1.0000x reference)
//
#include <hip/hip_runtime.h>
#include <hip/hip_bf16.h>

// Centroid update: out[c,:] = 0.3 * mean_{y[i]==c}(embed[i,:]) + 0.7 * centroid[c,:]
//
// R4 = R3 pipeline + MEASUREMENT PROBE. The R3 counting-sort pipeline is
// unchanged (memset, k1 histogram, k2 scan, k3 scatter, k4 gather). Before
// the real k4, three extra k4 dispatches gather from disjoint L3-cold 128MiB
// regions of d_ws (same order[] indices -> identical traffic shape) writing
// to ws scratch. dur_us - 220 = 3 x true cold gather cost. If the gather is
// >=77us it will also surface directly in the rocprof top-5.

#define BATCH       32768
#define EMBED_DIM   1024
#define NUM_CLASSES 1000
#define FACTOR      0.3f

__global__ __launch_bounds__(256) void k1_count(const int* __restrict__ y,
                                                int* __restrict__ counts) {
    const int i = blockIdx.x * 256 + threadIdx.x;
    atomicAdd(&counts[y[i]], 1);
}

__global__ __launch_bounds__(1024) void k2_scan(const int* __restrict__ counts,
                                                int* __restrict__ offsets,
                                                int* __restrict__ cursor) {
    __shared__ int s[1024];
    const int t = threadIdx.x;
    int v = (t < NUM_CLASSES) ? counts[t] : 0;
    s[t] = v;
    __syncthreads();
    #pragma unroll
    for (int d = 1; d < 1024; d <<= 1) {
        int add = (t >= d) ? s[t - d] : 0;
        __syncthreads();
        s[t] += add;
        __syncthreads();
    }
    const int excl = s[t] - v;
    if (t < NUM_CLASSES) {
        offsets[t] = excl;
        cursor[t]  = excl;
    }
}

__global__ __launch_bounds__(256) void k3_scatter(const int* __restrict__ y,
                                                  int* __restrict__ cursor,
                                                  int* __restrict__ order) {
    const int i = blockIdx.x * 256 + threadIdx.x;
    const int p = atomicAdd(&cursor[y[i]], 1);
    order[p] = i;
}

__global__ __launch_bounds__(256) void k4_gather(const float* __restrict__ embed,
                                                 const float* __restrict__ centroid,
                                                 const int* __restrict__ counts,
                                                 const int* __restrict__ offsets,
                                                 const int* __restrict__ order,
                                                 float* __restrict__ out) {
    const int c   = blockIdx.x;
    const int tid = threadIdx.x;
    const int d   = tid * 4;

    const int m    = counts[c];
    const int base = offsets[c];
    const int* __restrict__ rows = order + base;

    float4 acc = make_float4(0.f, 0.f, 0.f, 0.f);
    int j = 0;
    for (; j + 8 <= m; j += 8) {
        const int r0 = rows[j+0], r1 = rows[j+1], r2 = rows[j+2], r3 = rows[j+3];
        const int r4 = rows[j+4], r5 = rows[j+5], r6 = rows[j+6], r7 = rows[j+7];
        const float4 v0 = *reinterpret_cast<const float4*>(embed + (size_t)r0 * EMBED_DIM + d);
        const float4 v1 = *reinterpret_cast<const float4*>(embed + (size_t)r1 * EMBED_DIM + d);
        const float4 v2 = *reinterpret_cast<const float4*>(embed + (size_t)r2 * EMBED_DIM + d);
        const float4 v3 = *reinterpret_cast<const float4*>(embed + (size_t)r3 * EMBED_DIM + d);
        const float4 v4 = *reinterpret_cast<const float4*>(embed + (size_t)r4 * EMBED_DIM + d);
        const float4 v5 = *reinterpret_cast<const float4*>(embed + (size_t)r5 * EMBED_DIM + d);
        const float4 v6 = *reinterpret_cast<const float4*>(embed + (size_t)r6 * EMBED_DIM + d);
        const float4 v7 = *reinterpret_cast<const float4*>(embed + (size_t)r7 * EMBED_DIM + d);
        acc.x += v0.x + v1.x + v2.x + v3.x + v4.x + v5.x + v6.x + v7.x;
        acc.y += v0.y + v1.y + v2.y + v3.y + v4.y + v5.y + v6.y + v7.y;
        acc.z += v0.z + v1.z + v2.z + v3.z + v4.z + v5.z + v6.z + v7.z;
        acc.w += v0.w + v1.w + v2.w + v3.w + v4.w + v5.w + v6.w + v7.w;
    }
    for (; j < m; ++j) {
        const int r = rows[j];
        const float4 v = *reinterpret_cast<const float4*>(embed + (size_t)r * EMBED_DIM + d);
        acc.x += v.x; acc.y += v.y; acc.z += v.z; acc.w += v.w;
    }

    const float inv = 1.0f / (float)m;
    const size_t o  = (size_t)c * EMBED_DIM + d;
    const float4 cen = *reinterpret_cast<const float4*>(centroid + o);
    float4 res;
    res.x = FACTOR * (acc.x * inv) + (1.0f - FACTOR) * cen.x;
    res.y = FACTOR * (acc.y * inv) + (1.0f - FACTOR) * cen.y;
    res.z = FACTOR * (acc.z * inv) + (1.0f - FACTOR) * cen.z;
    res.w = FACTOR * (acc.w * inv) + (1.0f - FACTOR) * cen.w;
    *reinterpret_cast<float4*>(out + o) = res;
}

extern "C" void kernel_launch(void* const* d_in, const int* in_sizes, int n_in,
                              void* d_out, int out_size, void* d_ws, size_t ws_size,
                              hipStream_t stream) {
    const float* embed    = (const float*)d_in[0];  // [32768, 1024]
    const int*   y        = (const int*)d_in[1];    // [32768]
    const float* centroid = (const float*)d_in[2];  // [1000, 1024]
    float*       out      = (float*)d_out;          // [1000, 1024]

    // ws layout: control block in first 1 MB, garbage-out scratch at 1 MB,
    // three disjoint 136 MB cold-read regions starting at 8 MB.
    char* ws = (char*)d_ws;
    int* counts  = (int*)ws;            // 1024 ints
    int* offsets = counts + 1024;
    int* cursor  = offsets + 1024;
    int* order   = cursor + 1024;       // 32768 ints
    float* gout  = (float*)(ws + (1u << 20));                  // 4 MB scratch
    float* gsrc0 = (float*)(ws + (size_t)8   * (1u << 20));    // 136 MB region
    float* gsrc1 = (float*)(ws + (size_t)144 * (1u << 20));
    float* gsrc2 = (float*)(ws + (size_t)280 * (1u << 20));    // ends at 416 MB < 512

    hipMemsetAsync(counts, 0, 1024 * sizeof(int), stream);
    k1_count  <<<BATCH / 256, 256, 0, stream>>>(y, counts);
    k2_scan   <<<1, 1024, 0, stream>>>(counts, offsets, cursor);
    k3_scatter<<<BATCH / 256, 256, 0, stream>>>(y, cursor, order);

    // --- probe: 3 cold gathers from ws garbage, identical traffic shape ---
    k4_gather <<<NUM_CLASSES, 256, 0, stream>>>(gsrc0, gsrc0, counts, offsets, order, gout);
    k4_gather <<<NUM_CLASSES, 256, 0, stream>>>(gsrc1, gsrc1, counts, offsets, order, gout);
    k4_gather <<<NUM_CLASSES, 256, 0, stream>>>(gsrc2, gsrc2, counts, offsets, order, gout);

    // --- real gather ---
    k4_gather <<<NUM_CLASSES, 256, 0, stream>>>(embed, centroid, counts, offsets, order, out);
}

// Round 6
// 208.754 us; speedup vs baseline: 1.5402x; 1.5402x over previous
//
#include <hip/hip_runtime.h>
#include <hip/hip_bf16.h>

// Centroid update: out[c,:] = 0.3 * mean_{y[i]==c}(embed[i,:]) + 0.7 * centroid[c,:]
//
// R6 = R5 with the nontemporal builtins fixed: they require a native clang
// vector type (ext_vector_type), not HIP_vector_type<float,4>.
//
// Structure (probe-validated in R4):
//   K1: histogram counts[c]          (int4-vectorized, global atomics)
//   K2: exclusive prefix -> offsets[c], cursor[c]  (one 1024-thread block)
//   K3: scatter row indices -> order[] grouped by class (int4-vectorized)
//   K4: per-class gather: 1000 blocks x 256 thr, x8-unrolled non-temporal
//       row loads (32KB in flight/block), mean+blend epilogue.
// R4 probe: cold gather ~34us (4.1 TB/s effective); harness-fixed floor
// ~170-180us (512MB ws poison fills at 77us dominate every rocprof top-5).

#define BATCH       32768
#define EMBED_DIM   1024
#define NUM_CLASSES 1000
#define FACTOR      0.3f

typedef float vf4 __attribute__((ext_vector_type(4)));   // native vector for nt builtins

__global__ __launch_bounds__(256) void k1_count(const int* __restrict__ y,
                                                int* __restrict__ counts) {
    const int i4 = blockIdx.x * 256 + threadIdx.x;          // 32 blocks
    const int4 yv = reinterpret_cast<const int4*>(y)[i4];
    atomicAdd(&counts[yv.x], 1);
    atomicAdd(&counts[yv.y], 1);
    atomicAdd(&counts[yv.z], 1);
    atomicAdd(&counts[yv.w], 1);
}

__global__ __launch_bounds__(1024) void k2_scan(const int* __restrict__ counts,
                                                int* __restrict__ offsets,
                                                int* __restrict__ cursor) {
    __shared__ int s[1024];
    const int t = threadIdx.x;
    int v = (t < NUM_CLASSES) ? counts[t] : 0;
    s[t] = v;
    __syncthreads();
    #pragma unroll
    for (int d = 1; d < 1024; d <<= 1) {
        int add = (t >= d) ? s[t - d] : 0;
        __syncthreads();
        s[t] += add;
        __syncthreads();
    }
    const int excl = s[t] - v;
    if (t < NUM_CLASSES) {
        offsets[t] = excl;
        cursor[t]  = excl;
    }
}

__global__ __launch_bounds__(256) void k3_scatter(const int* __restrict__ y,
                                                  int* __restrict__ cursor,
                                                  int* __restrict__ order) {
    const int i4 = blockIdx.x * 256 + threadIdx.x;          // 32 blocks
    const int4 yv = reinterpret_cast<const int4*>(y)[i4];
    const int base = i4 * 4;
    { const int p = atomicAdd(&cursor[yv.x], 1); order[p] = base + 0; }
    { const int p = atomicAdd(&cursor[yv.y], 1); order[p] = base + 1; }
    { const int p = atomicAdd(&cursor[yv.z], 1); order[p] = base + 2; }
    { const int p = atomicAdd(&cursor[yv.w], 1); order[p] = base + 3; }
}

__global__ __launch_bounds__(256) void k4_gather(const float* __restrict__ embed,
                                                 const float* __restrict__ centroid,
                                                 const int* __restrict__ counts,
                                                 const int* __restrict__ offsets,
                                                 const int* __restrict__ order,
                                                 float* __restrict__ out) {
    const int c   = blockIdx.x;
    const int tid = threadIdx.x;
    const int d   = tid * 4;

    const int m    = counts[c];
    const int base = offsets[c];
    const int* __restrict__ rows = order + base;

    vf4 acc = (vf4)(0.f);
    int j = 0;
    for (; j + 8 <= m; j += 8) {
        const int r0 = rows[j+0], r1 = rows[j+1], r2 = rows[j+2], r3 = rows[j+3];
        const int r4 = rows[j+4], r5 = rows[j+5], r6 = rows[j+6], r7 = rows[j+7];
        // Non-temporal: each embed row is read exactly once device-wide.
        const vf4 v0 = __builtin_nontemporal_load(reinterpret_cast<const vf4*>(embed + (size_t)r0 * EMBED_DIM + d));
        const vf4 v1 = __builtin_nontemporal_load(reinterpret_cast<const vf4*>(embed + (size_t)r1 * EMBED_DIM + d));
        const vf4 v2 = __builtin_nontemporal_load(reinterpret_cast<const vf4*>(embed + (size_t)r2 * EMBED_DIM + d));
        const vf4 v3 = __builtin_nontemporal_load(reinterpret_cast<const vf4*>(embed + (size_t)r3 * EMBED_DIM + d));
        const vf4 v4 = __builtin_nontemporal_load(reinterpret_cast<const vf4*>(embed + (size_t)r4 * EMBED_DIM + d));
        const vf4 v5 = __builtin_nontemporal_load(reinterpret_cast<const vf4*>(embed + (size_t)r5 * EMBED_DIM + d));
        const vf4 v6 = __builtin_nontemporal_load(reinterpret_cast<const vf4*>(embed + (size_t)r6 * EMBED_DIM + d));
        const vf4 v7 = __builtin_nontemporal_load(reinterpret_cast<const vf4*>(embed + (size_t)r7 * EMBED_DIM + d));
        acc += v0 + v1 + v2 + v3 + v4 + v5 + v6 + v7;
    }
    for (; j < m; ++j) {
        const int r = rows[j];
        const vf4 v = __builtin_nontemporal_load(reinterpret_cast<const vf4*>(embed + (size_t)r * EMBED_DIM + d));
        acc += v;
    }

    const float inv = 1.0f / (float)m;   // m==0 -> inf -> NaN, matches reference
    const size_t o  = (size_t)c * EMBED_DIM + d;
    const vf4 cen = *reinterpret_cast<const vf4*>(centroid + o);
    const vf4 res = FACTOR * (acc * inv) + (1.0f - FACTOR) * cen;
    __builtin_nontemporal_store(res, reinterpret_cast<vf4*>(out + o));
}

extern "C" void kernel_launch(void* const* d_in, const int* in_sizes, int n_in,
                              void* d_out, int out_size, void* d_ws, size_t ws_size,
                              hipStream_t stream) {
    const float* embed    = (const float*)d_in[0];  // [32768, 1024]
    const int*   y        = (const int*)d_in[1];    // [32768]
    const float* centroid = (const float*)d_in[2];  // [1000, 1024]
    float*       out      = (float*)d_out;          // [1000, 1024]

    int* counts  = (int*)d_ws;          // 1024 ints
    int* offsets = counts + 1024;       // 1024 ints
    int* cursor  = offsets + 1024;      // 1024 ints
    int* order   = cursor + 1024;       // 32768 ints

    (void)hipMemsetAsync(counts, 0, 1024 * sizeof(int), stream);   // ws poisoned 0xAA
    k1_count  <<<BATCH / 1024, 256, 0, stream>>>(y, counts);
    k2_scan   <<<1, 1024, 0, stream>>>(counts, offsets, cursor);
    k3_scatter<<<BATCH / 1024, 256, 0, stream>>>(y, cursor, order);
    k4_gather <<<NUM_CLASSES, 256, 0, stream>>>(embed, centroid, counts, offsets, order, out);
}